// Round 2
// baseline (529.725 us; speedup 1.0000x reference)
//
#include <hip/hip_runtime.h>

#define NP   4096      // patches
#define DD   768       // embed dim
#define HD   64
#define WD   64
#define KTOP 100
#define BIGL 4097      // N+1

// ---------------- kernel 0: zero counts ----------------
__global__ void k_zero(int* __restrict__ p, int n) {
    int i = blockIdx.x * 256 + threadIdx.x;
    if (i < n) p[i] = 0;
}

// ---------------- kernel 1: per-column nonneg counts of sim = A*A^T ----------------
// Upper-triangular 128x128 tile grid (528 blocks). fp32, 8x8 micro-tile.
#define BK 16
__global__ __launch_bounds__(256) void k_count(const float* __restrict__ A,
                                               int* __restrict__ counts) {
    __shared__ float As[BK][128];
    __shared__ float Bs[BK][128];
    __shared__ int colc[128];
    __shared__ int rowc[128];

    // linear block id -> (bi, bj), bi <= bj, 32 row-tiles
    int b = blockIdx.x;
    int r = 0, rem = b;
    while (rem >= (32 - r)) { rem -= (32 - r); r++; }
    int bi = r, bj = r + rem;
    int i0 = bi * 128, j0 = bj * 128;

    int tid = threadIdx.x;
    int lrow = tid >> 1;            // 0..127 loader row
    int lk   = (tid & 1) * 8;       // k offset 0 or 8
    int tx = tid & 15, ty = tid >> 4;

    float acc[8][8];
#pragma unroll
    for (int a = 0; a < 8; a++)
#pragma unroll
        for (int c = 0; c < 8; c++) acc[a][c] = 0.f;

    for (int k0 = 0; k0 < DD; k0 += BK) {
        const float* pa = &A[(size_t)(i0 + lrow) * DD + k0 + lk];
        const float* pb = &A[(size_t)(j0 + lrow) * DD + k0 + lk];
        float4 a0 = ((const float4*)pa)[0];
        float4 a1 = ((const float4*)pa)[1];
        float4 b0 = ((const float4*)pb)[0];
        float4 b1 = ((const float4*)pb)[1];
        __syncthreads();   // previous iteration's LDS reads done
        As[lk + 0][lrow] = a0.x; As[lk + 1][lrow] = a0.y;
        As[lk + 2][lrow] = a0.z; As[lk + 3][lrow] = a0.w;
        As[lk + 4][lrow] = a1.x; As[lk + 5][lrow] = a1.y;
        As[lk + 6][lrow] = a1.z; As[lk + 7][lrow] = a1.w;
        Bs[lk + 0][lrow] = b0.x; Bs[lk + 1][lrow] = b0.y;
        Bs[lk + 2][lrow] = b0.z; Bs[lk + 3][lrow] = b0.w;
        Bs[lk + 4][lrow] = b1.x; Bs[lk + 5][lrow] = b1.y;
        Bs[lk + 6][lrow] = b1.z; Bs[lk + 7][lrow] = b1.w;
        __syncthreads();
#pragma unroll
        for (int kk = 0; kk < BK; kk++) {
            float ar[8], br[8];
            *(float4*)&ar[0] = *(const float4*)&As[kk][ty * 8];
            *(float4*)&ar[4] = *(const float4*)&As[kk][ty * 8 + 4];
            *(float4*)&br[0] = *(const float4*)&Bs[kk][tx * 8];
            *(float4*)&br[4] = *(const float4*)&Bs[kk][tx * 8 + 4];
#pragma unroll
            for (int a = 0; a < 8; a++)
#pragma unroll
                for (int c = 0; c < 8; c++) acc[a][c] += ar[a] * br[c];
        }
    }

    if (tid < 128) { colc[tid] = 0; rowc[tid] = 0; }
    __syncthreads();

    // column counts: per thread sum 8 rows for each of its 8 cols, reduce over ty-in-wave
    {
        int cc[8];
#pragma unroll
        for (int c = 0; c < 8; c++) {
            int v = 0;
#pragma unroll
            for (int a = 0; a < 8; a++) v += (acc[a][c] >= 0.f) ? 1 : 0;
            v += __shfl_xor(v, 16);
            v += __shfl_xor(v, 32);
            cc[c] = v;
        }
        if ((tid & 0x30) == 0) {   // one lane per tx per wave
#pragma unroll
            for (int c = 0; c < 8; c++) atomicAdd(&colc[tx * 8 + c], cc[c]);
        }
    }
    // row counts (transpose contribution), skip on diagonal tiles
    if (bi != bj) {
        int rc[8];
#pragma unroll
        for (int a = 0; a < 8; a++) {
            int v = 0;
#pragma unroll
            for (int c = 0; c < 8; c++) v += (acc[a][c] >= 0.f) ? 1 : 0;
            v += __shfl_xor(v, 1);
            v += __shfl_xor(v, 2);
            v += __shfl_xor(v, 4);
            v += __shfl_xor(v, 8);
            rc[a] = v;
        }
        if (tx == 0) {
#pragma unroll
            for (int a = 0; a < 8; a++) atomicAdd(&rowc[ty * 8 + a], rc[a]);
        }
    }
    __syncthreads();
    if (tid < 128) {
        atomicAdd(&counts[j0 + tid], colc[tid]);
        if (bi != bj) atomicAdd(&counts[i0 + tid], rowc[tid]);
    }
}

// ---------------- kernel 2: argmin(counts) -> blended seed ----------------
__global__ void k_seed(const int* __restrict__ counts, const int* __restrict__ attn_seed,
                       int* __restrict__ seedp) {
    __shared__ int bestC[256];
    __shared__ int bestI[256];
    int tid = threadIdx.x;
    int bc = 0x7fffffff, bI = 0;
    for (int j = tid; j < NP; j += 256) {
        int c = counts[j];
        if (c < bc) { bc = c; bI = j; }
    }
    bestC[tid] = bc; bestI[tid] = bI;
    __syncthreads();
    for (int st = 128; st > 0; st >>= 1) {
        if (tid < st) {
            if (bestC[tid + st] < bestC[tid] ||
                (bestC[tid + st] == bestC[tid] && bestI[tid + st] < bestI[tid])) {
                bestC[tid] = bestC[tid + st];
                bestI[tid] = bestI[tid + st];
            }
        }
        __syncthreads();
    }
    if (tid == 0) {
        int flat = bestI[0];
        int sr = flat / WD, sc = flat % WD;
        int vr = sr + attn_seed[0];
        int vc = sc + attn_seed[1];
        int rr, rc;
        if ((vr & 1) == 0) rr = vr >> 1;
        else { int m = vr >> 1; rr = (m & 1) ? m + 1 : m; }   // round-half-to-even
        if ((vc & 1) == 0) rc = vc >> 1;
        else { int m = vc >> 1; rc = (m & 1) ? m + 1 : m; }
        seedp[0] = rr * WD + rc;
    }
}

// ---------------- kernel 3: sim[seed, :] row ----------------
__global__ __launch_bounds__(256) void k_simrow(const float* __restrict__ A,
                                                const int* __restrict__ seedp,
                                                float* __restrict__ simrow) {
    __shared__ float sv[DD];
    __shared__ float red[4];
    int seed = seedp[0];
    int tid = threadIdx.x;
    for (int k = tid; k < DD; k += 256) sv[k] = A[(size_t)seed * DD + k];
    __syncthreads();
    int jbase = blockIdx.x * 16;
    for (int jj = 0; jj < 16; jj++) {
        int j = jbase + jj;
        float p = 0.f;
        for (int k = tid; k < DD; k += 256) p += sv[k] * A[(size_t)j * DD + k];
        for (int o = 32; o > 0; o >>= 1) p += __shfl_down(p, o);
        if ((tid & 63) == 0) red[tid >> 6] = p;
        __syncthreads();
        if (tid == 0) simrow[j] = red[0] + red[1] + red[2] + red[3];
        __syncthreads();
    }
}

// ---------------- kernel 4: stable-argsort rank -> initial expansion set s ----------------
__global__ __launch_bounds__(256) void k_rank(const float* __restrict__ simrow,
                                              const int* __restrict__ seedp,
                                              int* __restrict__ s) {
    __shared__ float v[NP];
    int tid = threadIdx.x;
    int j = blockIdx.x * 256 + tid;
    for (int k = tid; k < NP; k += 256) v[k] = simrow[k];
    __syncthreads();
    float mv = v[j];
    int rank = 0;
    for (int jp = 0; jp < NP; jp++) {
        float u = v[jp];
        rank += (u > mv || (u == mv && jp < j)) ? 1 : 0;   // stable descending
    }
    int seed = seedp[0];
    int sv = 0;
    if (rank < KTOP) sv = (mv >= 0.f || j == seed) ? 1 : 0;
    s[j] = sv;
}

// ---------------- kernel 5a: compact active indices (sorted ascending) ----------------
__global__ void k_compact(const int* __restrict__ s, int* __restrict__ act,
                          int* __restrict__ Mp) {
    __shared__ int pre[256];
    int tid = threadIdx.x;
    int c = 0;
    for (int n = 0; n < 16; n++) c += (s[tid * 16 + n] != 0) ? 1 : 0;
    pre[tid] = c;
    __syncthreads();
    if (tid == 0) {
        int run = 0;
        for (int i = 0; i < 256; i++) { int t = pre[i]; pre[i] = run; run += t; }
        Mp[0] = run;
    }
    __syncthreads();
    int off = pre[tid];
    for (int n = 0; n < 16; n++) {
        int idx = tid * 16 + n;
        if (s[idx] != 0) act[off++] = idx;
    }
}

// ---------------- kernel 5b: subsim rows, lane-parallel coalesced dots ----------------
__global__ __launch_bounds__(256) void k_subsim(const float* __restrict__ A,
                                                const int* __restrict__ act,
                                                const int* __restrict__ Mp,
                                                float* __restrict__ subsim) {
    __shared__ float av[DD];
    int M = Mp[0];
    int p = blockIdx.x;
    if (p >= M) return;
    int tid = threadIdx.x, lane = tid & 63, w = tid >> 6;
    int ip = act[p];
    for (int k = tid; k < DD; k += 256) av[k] = A[(size_t)ip * DD + k];
    __syncthreads();
    for (int q = w; q < M; q += 4) {
        int iq = act[q];
        float sum = 0.f;
        for (int k = lane; k < DD; k += 64) sum += av[k] * A[(size_t)iq * DD + k];
        for (int o = 32; o > 0; o >>= 1) sum += __shfl_down(sum, o);
        if (lane == 0) subsim[p * 128 + q] = sum;
    }
}

// ---------------- kernel 6: expansion scan (LDS) + CC on <=100 nodes ----------------
__global__ __launch_bounds__(256) void k_finish(const float* __restrict__ subsim,
                                                const int* __restrict__ act,
                                                const int* __restrict__ Mp,
                                                int* __restrict__ outp) {
    __shared__ float ss[128 * 128];   // 64 KB
    __shared__ int alive[128];
    __shared__ int lab[128];
    __shared__ int yy[128], xx[128];
    __shared__ int chg;
    int M = Mp[0];
    int tid = threadIdx.x;

    for (int idx = tid; idx < M * 128; idx += 256) ss[idx] = subsim[idx];
    if (tid < 128) alive[tid] = 0;
    __syncthreads();

    // sequential expansion scan, wave 0 only (LDS-resident)
    if (tid < 64) {
        int lane = tid;
        float al = (lane < M) ? 1.f : 0.f;
        float ah = (lane + 64 < M) ? 1.f : 0.f;
        for (int p = 0; p < M; p++) {
            float part = 0.f;
            if (lane < M)      part += ss[p * 128 + lane] * al;
            if (lane + 64 < M) part += ss[p * 128 + lane + 64] * ah;
#pragma unroll
            for (int o = 1; o < 64; o <<= 1) part += __shfl_xor(part, o);
            if (!(part > 0.f)) {
                if (lane == p)      al = 0.f;
                if (lane + 64 == p) ah = 0.f;
            }
        }
        alive[lane] = (lane < M && al != 0.f) ? 1 : 0;
        alive[lane + 64] = (lane + 64 < M && ah != 0.f) ? 1 : 0;
    }
    __syncthreads();

    // connected components over alive nodes (8-connectivity, min-label Jacobi)
    if (tid < 128) {
        int a = (tid < M) ? alive[tid] : 0;
        int id = a ? act[tid] : 0;
        yy[tid] = a ? (id >> 6) : -1000;
        xx[tid] = a ? (id & 63) : -1000;
        lab[tid] = a ? (id + 1) : BIGL;
    }
    __syncthreads();
    while (true) {
        if (tid == 0) chg = 0;
        __syncthreads();
        int local = 0;
        if (tid < M && alive[tid]) {
            int m = lab[tid];
            int y = yy[tid], x = xx[tid];
            for (int q = 0; q < M; q++) {
                int dy = yy[q] - y;
                if (dy < -1 || dy > 1) continue;
                int dx = xx[q] - x;
                if (dx < -1 || dx > 1) continue;
                int u = lab[q];
                if (u < m) m = u;
            }
            if (m < lab[tid]) { lab[tid] = m; local = 1; }
        }
        if (local) chg = 1;
        __syncthreads();
        if (chg == 0) break;
        __syncthreads();
    }

    for (int n = tid; n < NP; n += 256) outp[n] = 0;
    __syncthreads();
    if (tid < M && alive[tid]) outp[act[tid]] = lab[tid];
}

extern "C" void kernel_launch(void* const* d_in, const int* in_sizes, int n_in,
                              void* d_out, int out_size, void* d_ws, size_t ws_size,
                              hipStream_t stream) {
    const float* A = (const float*)d_in[0];       // out: (4096, 768) fp32
    const int* attn = (const int*)d_in[1];        // attn_seed: (2,) int32
    int* outp = (int*)d_out;                      // labels: (64,64) int32

    char* ws = (char*)d_ws;
    int*   counts = (int*)(ws);                   // 4096 ints
    float* simrow = (float*)(ws + 16384);         // 4096 floats
    int*   s      = (int*)(ws + 32768);           // 4096 ints
    int*   act    = (int*)(ws + 49152);           // 128 ints
    int*   Mp     = (int*)(ws + 49152 + 512);
    int*   seedp  = (int*)(ws + 49152 + 516);
    float* subsim = (float*)(ws + 50176);         // 128*128 floats

    k_zero   <<<16,  256, 0, stream>>>(counts, NP);
    k_count  <<<528, 256, 0, stream>>>(A, counts);
    k_seed   <<<1,   256, 0, stream>>>(counts, attn, seedp);
    k_simrow <<<256, 256, 0, stream>>>(A, seedp, simrow);
    k_rank   <<<16,  256, 0, stream>>>(simrow, seedp, s);
    k_compact<<<1,   256, 0, stream>>>(s, act, Mp);
    k_subsim <<<128, 256, 0, stream>>>(A, act, Mp, subsim);
    k_finish <<<1,   256, 0, stream>>>(subsim, act, Mp, outp);
}

// Round 3
// 396.493 us; speedup vs baseline: 1.3360x; 1.3360x over previous
//
#include <hip/hip_runtime.h>
#include <cstdint>

#define NP   4096      // patches
#define DD   768       // embed dim
#define HD   64
#define WD   64
#define KTOP 100
#define BIGL 4097      // N+1

typedef short bf16x8 __attribute__((ext_vector_type(8)));
typedef float f32x4  __attribute__((ext_vector_type(4)));

__device__ __forceinline__ void gload_lds16(const void* g, void* l) {
    __builtin_amdgcn_global_load_lds(
        (const __attribute__((address_space(1))) unsigned int*)(uintptr_t)g,
        (__attribute__((address_space(3))) unsigned int*)(unsigned int)(uintptr_t)l,
        16, 0, 0);
}

__device__ __forceinline__ unsigned short f2bf_rne(float x) {
    unsigned b = __float_as_uint(x);
    unsigned r = b + 0x7FFFu + ((b >> 16) & 1u);
    return (unsigned short)(r >> 16);
}
__device__ __forceinline__ float bf2f(unsigned short h) {
    return __uint_as_float(((unsigned)h) << 16);
}

// ---------------- kernel 1: split A into bf16 hi + bf16 lo; zero counts ----------------
__global__ __launch_bounds__(256) void k_split(const float* __restrict__ A,
                                               unsigned short* __restrict__ hi,
                                               unsigned short* __restrict__ lo,
                                               int* __restrict__ counts) {
    if (blockIdx.x < 16) counts[blockIdx.x * 256 + threadIdx.x] = 0;
    int idx = blockIdx.x * 256 + threadIdx.x;       // float4 index
    float4 v = ((const float4*)A)[idx];
    unsigned short h0 = f2bf_rne(v.x), h1 = f2bf_rne(v.y),
                   h2 = f2bf_rne(v.z), h3 = f2bf_rne(v.w);
    unsigned short l0 = f2bf_rne(v.x - bf2f(h0)), l1 = f2bf_rne(v.y - bf2f(h1)),
                   l2 = f2bf_rne(v.z - bf2f(h2)), l3 = f2bf_rne(v.w - bf2f(h3));
    ushort4 hv = make_ushort4(h0, h1, h2, h3);
    ushort4 lv = make_ushort4(l0, l1, l2, l3);
    ((ushort4*)hi)[idx] = hv;
    ((ushort4*)lo)[idx] = lv;
}

// ---------------- kernel 2: split-bf16 MFMA GEMM -> per-column nonneg counts ----------------
// Triangular 128x128 tile grid (528 blocks). K=2304 = [hi|lo|hi]·[hi|hi|lo].
// LDS tiles: 128 rows x 64 bf16, row stride 128B = 8 chunks of 16B.
// XOR swizzle: phys_chunk(row,kc) = row*8 + (kc ^ (row&7)) -> conflict-free frag reads
// while preserving global_load_lds's wave-uniform-base + lane*16 LDS layout.
__global__ __launch_bounds__(256) void k_gemm(const unsigned short* __restrict__ hi,
                                              const unsigned short* __restrict__ lo,
                                              int* __restrict__ counts) {
    __shared__ __align__(16) unsigned short As[128 * 64];   // 16 KB
    __shared__ __align__(16) unsigned short Bs[128 * 64];   // 16 KB
    __shared__ int colc[128];
    __shared__ int rowc[128];

    // linear block id -> (bi, bj), bi <= bj, 32 row-tiles
    int b = blockIdx.x;
    int r = 0, rem = b;
    while (rem >= (32 - r)) { rem -= (32 - r); ++r; }
    int bi = r, bj = r + rem;
    int i0 = bi * 128, j0 = bj * 128;

    int tid = threadIdx.x;
    int lane = tid & 63, w = tid >> 6;
    int wm = w & 1, wn = w >> 1;      // wave quadrant: rows wm*64, cols wn*64

    f32x4 acc[4][4];
#pragma unroll
    for (int ti = 0; ti < 4; ++ti)
#pragma unroll
        for (int tj = 0; tj < 4; ++tj) { acc[ti][tj][0] = 0.f; acc[ti][tj][1] = 0.f;
                                         acc[ti][tj][2] = 0.f; acc[ti][tj][3] = 0.f; }

    for (int it = 0; it < 36; ++it) {
        int seg = it / 12;                 // 0: hi.hi  1: lo.hi  2: hi.lo
        int kbase = (it % 12) * 64;
        const unsigned short* aS = (seg == 1) ? lo : hi;
        const unsigned short* bS = (seg == 2) ? lo : hi;
        __syncthreads();   // previous iteration's LDS reads done
#pragma unroll
        for (int q = 0; q < 4; ++q) {
            int p = q * 256 + tid;               // 16B chunk id, 1024 per tile
            int row = p >> 3, kcp = p & 7;
            int kclog = kcp ^ (row & 7);
            const unsigned short* ga = aS + (size_t)(i0 + row) * DD + kbase + kclog * 8;
            const unsigned short* gb = bS + (size_t)(j0 + row) * DD + kbase + kclog * 8;
            gload_lds16(ga, &As[p * 8]);
            gload_lds16(gb, &Bs[p * 8]);
        }
        __syncthreads();   // compiler drains vmcnt before barrier
#pragma unroll
        for (int s = 0; s < 2; ++s) {
            bf16x8 af[4], bfr[4];
#pragma unroll
            for (int t = 0; t < 4; ++t) {
                int arow = wm * 64 + t * 16 + (lane & 15);
                int kc = s * 4 + (lane >> 4);
                int pa = arow * 8 + (kc ^ (arow & 7));
                af[t] = *(const bf16x8*)&As[pa * 8];
                int brow = wn * 64 + t * 16 + (lane & 15);
                int pb = brow * 8 + (kc ^ (brow & 7));
                bfr[t] = *(const bf16x8*)&Bs[pb * 8];
            }
#pragma unroll
            for (int ti = 0; ti < 4; ++ti)
#pragma unroll
                for (int tj = 0; tj < 4; ++tj)
                    acc[ti][tj] = __builtin_amdgcn_mfma_f32_16x16x32_bf16(
                        af[ti], bfr[tj], acc[ti][tj], 0, 0, 0);
        }
    }

    if (tid < 128) { colc[tid] = 0; rowc[tid] = 0; }
    __syncthreads();

    int nl = lane & 15;     // col within 16x16 tile
    int rg = lane >> 4;     // row group (rows rg*4 + reg)
#pragma unroll
    for (int ti = 0; ti < 4; ++ti)
#pragma unroll
        for (int tj = 0; tj < 4; ++tj) {
            f32x4 a = acc[ti][tj];
            int c4 = ((a[0] >= 0.f) ? 1 : 0) + ((a[1] >= 0.f) ? 1 : 0) +
                     ((a[2] >= 0.f) ? 1 : 0) + ((a[3] >= 0.f) ? 1 : 0);
            int ct = c4;
            ct += __shfl_xor(ct, 16);
            ct += __shfl_xor(ct, 32);
            if (rg == 0) atomicAdd(&colc[wn * 64 + tj * 16 + nl], ct);
            if (bi != bj) {
#pragma unroll
                for (int g = 0; g < 4; ++g) {
                    int rv = (a[g] >= 0.f) ? 1 : 0;
                    rv += __shfl_xor(rv, 1);
                    rv += __shfl_xor(rv, 2);
                    rv += __shfl_xor(rv, 4);
                    rv += __shfl_xor(rv, 8);
                    if (nl == 0) atomicAdd(&rowc[wm * 64 + ti * 16 + rg * 4 + g], rv);
                }
            }
        }
    __syncthreads();
    if (tid < 128) {
        atomicAdd(&counts[j0 + tid], colc[tid]);
        if (bi != bj) atomicAdd(&counts[i0 + tid], rowc[tid]);
    }
}

// ---------------- kernel 3: argmin(counts) -> blended seed ----------------
__global__ void k_seed(const int* __restrict__ counts, const int* __restrict__ attn_seed,
                       int* __restrict__ seedp) {
    __shared__ int bestC[256];
    __shared__ int bestI[256];
    int tid = threadIdx.x;
    int bc = 0x7fffffff, bI = 0;
    for (int j = tid; j < NP; j += 256) {
        int c = counts[j];
        if (c < bc) { bc = c; bI = j; }
    }
    bestC[tid] = bc; bestI[tid] = bI;
    __syncthreads();
    for (int st = 128; st > 0; st >>= 1) {
        if (tid < st) {
            if (bestC[tid + st] < bestC[tid] ||
                (bestC[tid + st] == bestC[tid] && bestI[tid + st] < bestI[tid])) {
                bestC[tid] = bestC[tid + st];
                bestI[tid] = bestI[tid + st];
            }
        }
        __syncthreads();
    }
    if (tid == 0) {
        int flat = bestI[0];
        int sr = flat / WD, sc = flat % WD;
        int vr = sr + attn_seed[0];
        int vc = sc + attn_seed[1];
        int rr, rc;
        if ((vr & 1) == 0) rr = vr >> 1;
        else { int m = vr >> 1; rr = (m & 1) ? m + 1 : m; }   // round-half-to-even
        if ((vc & 1) == 0) rc = vc >> 1;
        else { int m = vc >> 1; rc = (m & 1) ? m + 1 : m; }
        seedp[0] = rr * WD + rc;
    }
}

// ---------------- kernel 4: sim[seed, :] row (fp32, exact as before) ----------------
__global__ __launch_bounds__(256) void k_simrow(const float* __restrict__ A,
                                                const int* __restrict__ seedp,
                                                float* __restrict__ simrow) {
    __shared__ float sv[DD];
    __shared__ float red[4];
    int seed = seedp[0];
    int tid = threadIdx.x;
    for (int k = tid; k < DD; k += 256) sv[k] = A[(size_t)seed * DD + k];
    __syncthreads();
    int jbase = blockIdx.x * 16;
    for (int jj = 0; jj < 16; jj++) {
        int j = jbase + jj;
        float p = 0.f;
        for (int k = tid; k < DD; k += 256) p += sv[k] * A[(size_t)j * DD + k];
        for (int o = 32; o > 0; o >>= 1) p += __shfl_down(p, o);
        if ((tid & 63) == 0) red[tid >> 6] = p;
        __syncthreads();
        if (tid == 0) simrow[j] = red[0] + red[1] + red[2] + red[3];
        __syncthreads();
    }
}

// ---------------- kernel 5: top-K selection + compact (single block) ----------------
// Kth-largest via 32-step bitwise search on sign-flipped float keys; stable ties by index.
__global__ __launch_bounds__(256) void k_select(const float* __restrict__ simrow,
                                                const int* __restrict__ seedp,
                                                int* __restrict__ act, int* __restrict__ Mp) {
    __shared__ unsigned key[NP];   // 16 KB
    __shared__ int pre[256];
    __shared__ int bcast;
    int tid = threadIdx.x;
    for (int j = tid; j < NP; j += 256) {
        unsigned b = __float_as_uint(simrow[j]);
        key[j] = (b & 0x80000000u) ? ~b : (b | 0x80000000u);   // monotone encode
    }
    __syncthreads();
    int base = tid * 16;
    unsigned prefix = 0;
    for (int bit = 31; bit >= 0; --bit) {
        unsigned cand = prefix | (1u << bit);
        int c = 0;
#pragma unroll
        for (int n = 0; n < 16; ++n) c += (key[base + n] >= cand) ? 1 : 0;
        pre[tid] = c;
        __syncthreads();
        if (tid == 0) { int t = 0; for (int i = 0; i < 256; ++i) t += pre[i]; bcast = t; }
        __syncthreads();
        if (bcast >= KTOP) prefix = cand;
        __syncthreads();
    }
    unsigned KT = prefix;   // Kth-largest key value
    int cgt = 0, ceq = 0;
#pragma unroll
    for (int n = 0; n < 16; ++n) {
        unsigned k = key[base + n];
        cgt += (k > KT) ? 1 : 0;
        ceq += (k == KT) ? 1 : 0;
    }
    pre[tid] = cgt;
    __syncthreads();
    if (tid == 0) { int t = 0; for (int i = 0; i < 256; ++i) t += pre[i]; bcast = t; }
    __syncthreads();
    int slots = KTOP - bcast;   // how many ==KT elements (by index order) stay in top-K
    __syncthreads();
    pre[tid] = ceq;
    __syncthreads();
    if (tid == 0) { int run = 0; for (int i = 0; i < 256; ++i) { int t = pre[i]; pre[i] = run; run += t; } }
    __syncthreads();
    int eqrun = pre[tid];
    int seed = seedp[0];
    int flag[16]; int cf = 0;
#pragma unroll
    for (int n = 0; n < 16; ++n) {
        int j = base + n;
        unsigned k = key[j];
        int topk = (k > KT) || (k == KT && eqrun < slots);
        if (k == KT) ++eqrun;
        int f = (topk && (k >= 0x80000000u || j == seed)) ? 1 : 0;   // sim>=0 or seed
        flag[n] = f; cf += f;
    }
    __syncthreads();
    pre[tid] = cf;
    __syncthreads();
    if (tid == 0) {
        int run = 0;
        for (int i = 0; i < 256; ++i) { int t = pre[i]; pre[i] = run; run += t; }
        Mp[0] = run;
    }
    __syncthreads();
    int off = pre[tid];
#pragma unroll
    for (int n = 0; n < 16; ++n)
        if (flag[n]) act[off++] = base + n;
}

// ---------------- kernel 6: subsim rows, lane-parallel coalesced dots ----------------
__global__ __launch_bounds__(256) void k_subsim(const float* __restrict__ A,
                                                const int* __restrict__ act,
                                                const int* __restrict__ Mp,
                                                float* __restrict__ subsim) {
    __shared__ float av[DD];
    int M = Mp[0];
    int p = blockIdx.x;
    if (p >= M) return;
    int tid = threadIdx.x, lane = tid & 63, w = tid >> 6;
    int ip = act[p];
    for (int k = tid; k < DD; k += 256) av[k] = A[(size_t)ip * DD + k];
    __syncthreads();
    for (int q = w; q < M; q += 4) {
        int iq = act[q];
        float sum = 0.f;
        for (int k = lane; k < DD; k += 64) sum += av[k] * A[(size_t)iq * DD + k];
        for (int o = 32; o > 0; o >>= 1) sum += __shfl_down(sum, o);
        if (lane == 0) subsim[p * 128 + q] = sum;
    }
}

// ---------------- kernel 7: expansion scan (LDS) + CC on <=100 nodes ----------------
__global__ __launch_bounds__(256) void k_finish(const float* __restrict__ subsim,
                                                const int* __restrict__ act,
                                                const int* __restrict__ Mp,
                                                int* __restrict__ outp) {
    __shared__ float ss[128 * 128];   // 64 KB
    __shared__ int alive[128];
    __shared__ int lab[128];
    __shared__ int yy[128], xx[128];
    __shared__ int chg;
    int M = Mp[0];
    int tid = threadIdx.x;

    for (int idx = tid; idx < M * 128; idx += 256) ss[idx] = subsim[idx];
    if (tid < 128) alive[tid] = 0;
    __syncthreads();

    // sequential expansion scan, wave 0 only (LDS-resident)
    if (tid < 64) {
        int lane = tid;
        float al = (lane < M) ? 1.f : 0.f;
        float ah = (lane + 64 < M) ? 1.f : 0.f;
        for (int p = 0; p < M; p++) {
            float part = 0.f;
            if (lane < M)      part += ss[p * 128 + lane] * al;
            if (lane + 64 < M) part += ss[p * 128 + lane + 64] * ah;
#pragma unroll
            for (int o = 1; o < 64; o <<= 1) part += __shfl_xor(part, o);
            if (!(part > 0.f)) {
                if (lane == p)      al = 0.f;
                if (lane + 64 == p) ah = 0.f;
            }
        }
        alive[lane] = (lane < M && al != 0.f) ? 1 : 0;
        alive[lane + 64] = (lane + 64 < M && ah != 0.f) ? 1 : 0;
    }
    __syncthreads();

    // connected components over alive nodes (8-connectivity, min-label)
    if (tid < 128) {
        int a = (tid < M) ? alive[tid] : 0;
        int id = a ? act[tid] : 0;
        yy[tid] = a ? (id >> 6) : -1000;
        xx[tid] = a ? (id & 63) : -1000;
        lab[tid] = a ? (id + 1) : BIGL;
    }
    __syncthreads();
    while (true) {
        if (tid == 0) chg = 0;
        __syncthreads();
        int local = 0;
        if (tid < M && alive[tid]) {
            int m = lab[tid];
            int y = yy[tid], x = xx[tid];
            for (int q = 0; q < M; q++) {
                int dy = yy[q] - y;
                if (dy < -1 || dy > 1) continue;
                int dx = xx[q] - x;
                if (dx < -1 || dx > 1) continue;
                int u = lab[q];
                if (u < m) m = u;
            }
            if (m < lab[tid]) { lab[tid] = m; local = 1; }
        }
        if (local) chg = 1;
        __syncthreads();
        if (chg == 0) break;
        __syncthreads();
    }

    for (int n = tid; n < NP; n += 256) outp[n] = 0;
    __syncthreads();
    if (tid < M && alive[tid]) outp[act[tid]] = lab[tid];
}

extern "C" void kernel_launch(void* const* d_in, const int* in_sizes, int n_in,
                              void* d_out, int out_size, void* d_ws, size_t ws_size,
                              hipStream_t stream) {
    const float* A = (const float*)d_in[0];       // out: (4096, 768) fp32
    const int* attn = (const int*)d_in[1];        // attn_seed: (2,) int32
    int* outp = (int*)d_out;                      // labels: (64,64) int32

    char* ws = (char*)d_ws;
    int*            counts = (int*)(ws);                    // 16 KB
    float*          simrow = (float*)(ws + 16384);          // 16 KB
    int*            act    = (int*)(ws + 32768);            // 512 B
    int*            Mp     = (int*)(ws + 33280);
    int*            seedp  = (int*)(ws + 33284);
    float*          subsim = (float*)(ws + 33792);          // 64 KB
    unsigned short* hi     = (unsigned short*)(ws + 1048576);           // 6.29 MB
    unsigned short* lo     = (unsigned short*)(ws + 1048576 + 6291456); // 6.29 MB

    k_split  <<<3072, 256, 0, stream>>>(A, hi, lo, counts);
    k_gemm   <<<528,  256, 0, stream>>>(hi, lo, counts);
    k_seed   <<<1,    256, 0, stream>>>(counts, attn, seedp);
    k_simrow <<<256,  256, 0, stream>>>(A, seedp, simrow);
    k_select <<<1,    256, 0, stream>>>(simrow, seedp, act, Mp);
    k_subsim <<<128,  256, 0, stream>>>(A, act, Mp, subsim);
    k_finish <<<1,    256, 0, stream>>>(subsim, act, Mp, outp);
}

// Round 4
// 333.148 us; speedup vs baseline: 1.5901x; 1.1901x over previous
//
#include <hip/hip_runtime.h>
#include <cstdint>

#define NP   4096      // patches
#define DD   768       // embed dim
#define HD   64
#define WD   64
#define KTOP 100
#define BIGL 4097      // N+1

typedef short bf16x8 __attribute__((ext_vector_type(8)));
typedef float f32x4  __attribute__((ext_vector_type(4)));

__device__ __forceinline__ void gload_lds16(const void* g, void* l) {
    __builtin_amdgcn_global_load_lds(
        (const __attribute__((address_space(1))) unsigned int*)(uintptr_t)g,
        (__attribute__((address_space(3))) unsigned int*)(unsigned int)(uintptr_t)l,
        16, 0, 0);
}

__device__ __forceinline__ unsigned short f2bf_rne(float x) {
    unsigned b = __float_as_uint(x);
    unsigned r = b + 0x7FFFu + ((b >> 16) & 1u);
    return (unsigned short)(r >> 16);
}
__device__ __forceinline__ float bf2f(unsigned short h) {
    return __uint_as_float(((unsigned)h) << 16);
}

// ---------------- kernel 1: split A into bf16 hi + bf16 lo; zero counts ----------------
__global__ __launch_bounds__(256) void k_split(const float* __restrict__ A,
                                               unsigned short* __restrict__ hi,
                                               unsigned short* __restrict__ lo,
                                               int* __restrict__ counts) {
    if (blockIdx.x < 16) counts[blockIdx.x * 256 + threadIdx.x] = 0;
    int idx = blockIdx.x * 256 + threadIdx.x;       // float4 index
    float4 v = ((const float4*)A)[idx];
    unsigned short h0 = f2bf_rne(v.x), h1 = f2bf_rne(v.y),
                   h2 = f2bf_rne(v.z), h3 = f2bf_rne(v.w);
    unsigned short l0 = f2bf_rne(v.x - bf2f(h0)), l1 = f2bf_rne(v.y - bf2f(h1)),
                   l2 = f2bf_rne(v.z - bf2f(h2)), l3 = f2bf_rne(v.w - bf2f(h3));
    ((ushort4*)hi)[idx] = make_ushort4(h0, h1, h2, h3);
    ((ushort4*)lo)[idx] = make_ushort4(l0, l1, l2, l3);
}

// ---------------- kernel 2: split-bf16 MFMA GEMM -> per-column nonneg counts ----------------
// Triangular 128x128 tiles, BK=128, XCD-locality supertile remap.
// LDS rows: 128 cols bf16 = 256B = 16 chunks of 16B; XOR swizzle kc^(row&15).
__global__ __launch_bounds__(256) void k_gemm(const unsigned short* __restrict__ hi,
                                              const unsigned short* __restrict__ lo,
                                              int* __restrict__ counts) {
    __shared__ __align__(16) unsigned short As[128 * 128];   // 32 KB
    __shared__ __align__(16) unsigned short Bs[128 * 128];   // 32 KB
    __shared__ int colc[128];
    __shared__ int rowc[128];

    // XCD-locality remap: XCD = blockIdx%8 (round-robin). Give each XCD a
    // contiguous run of 66 tiles in supertile-grouped enumeration so its
    // co-resident blocks share ~16 strips (fits 4 MiB L2).
    int t = ((blockIdx.x & 7) * 66) + (blockIdx.x >> 3);
    int SI = 0, SJ = 0, rem = t;
    for (;;) {
        int sz = (SI == SJ) ? 36 : 64;
        if (rem < sz) break;
        rem -= sz;
        if (++SJ == 4) { ++SI; SJ = SI; }
    }
    int li, lj;
    if (SI == SJ) {
        int r = 0;
        while (rem >= (8 - r)) { rem -= (8 - r); ++r; }
        li = r; lj = r + rem;
    } else { li = rem >> 3; lj = rem & 7; }
    int bi = SI * 8 + li, bj = SJ * 8 + lj;
    int i0 = bi * 128, j0 = bj * 128;

    int tid = threadIdx.x;
    int lane = tid & 63, w = tid >> 6;
    int wm = w & 1, wn = w >> 1;      // wave quadrant: rows wm*64, cols wn*64

    f32x4 acc[4][4];
#pragma unroll
    for (int ti = 0; ti < 4; ++ti)
#pragma unroll
        for (int tj = 0; tj < 4; ++tj) { acc[ti][tj][0] = 0.f; acc[ti][tj][1] = 0.f;
                                         acc[ti][tj][2] = 0.f; acc[ti][tj][3] = 0.f; }

    for (int it = 0; it < 18; ++it) {
        int seg = it / 6;                  // 0: hi.hi  1: lo.hi  2: hi.lo
        int kbase = (it % 6) * 128;
        const unsigned short* aS = (seg == 1) ? lo : hi;
        const unsigned short* bS = (seg == 2) ? lo : hi;
        __syncthreads();   // previous iteration's LDS reads done
#pragma unroll
        for (int q = 0; q < 8; ++q) {
            int p = q * 256 + tid;               // 16B chunk id, 2048 per tile
            int row = p >> 4, kcp = p & 15;
            int kclog = kcp ^ (row & 15);
            const unsigned short* ga = aS + (size_t)(i0 + row) * DD + kbase + kclog * 8;
            const unsigned short* gb = bS + (size_t)(j0 + row) * DD + kbase + kclog * 8;
            gload_lds16(ga, &As[p * 8]);
            gload_lds16(gb, &Bs[p * 8]);
        }
        __syncthreads();
#pragma unroll
        for (int s = 0; s < 4; ++s) {
            bf16x8 af[4], bfr[4];
#pragma unroll
            for (int tt = 0; tt < 4; ++tt) {
                int arow = wm * 64 + tt * 16 + (lane & 15);
                int kc = s * 4 + (lane >> 4);
                int pa = arow * 16 + (kc ^ (arow & 15));
                af[tt] = *(const bf16x8*)&As[pa * 8];
                int brow = wn * 64 + tt * 16 + (lane & 15);
                int pb = brow * 16 + (kc ^ (brow & 15));
                bfr[tt] = *(const bf16x8*)&Bs[pb * 8];
            }
#pragma unroll
            for (int ti = 0; ti < 4; ++ti)
#pragma unroll
                for (int tj = 0; tj < 4; ++tj)
                    acc[ti][tj] = __builtin_amdgcn_mfma_f32_16x16x32_bf16(
                        af[ti], bfr[tj], acc[ti][tj], 0, 0, 0);
        }
    }

    if (tid < 128) { colc[tid] = 0; rowc[tid] = 0; }
    __syncthreads();

    int nl = lane & 15;     // col within 16x16 tile
    int rg = lane >> 4;     // row group (rows rg*4 + reg)
#pragma unroll
    for (int ti = 0; ti < 4; ++ti)
#pragma unroll
        for (int tj = 0; tj < 4; ++tj) {
            f32x4 a = acc[ti][tj];
            int c4 = ((a[0] >= 0.f) ? 1 : 0) + ((a[1] >= 0.f) ? 1 : 0) +
                     ((a[2] >= 0.f) ? 1 : 0) + ((a[3] >= 0.f) ? 1 : 0);
            int ct = c4;
            ct += __shfl_xor(ct, 16);
            ct += __shfl_xor(ct, 32);
            if (rg == 0) atomicAdd(&colc[wn * 64 + tj * 16 + nl], ct);
            if (bi != bj) {
#pragma unroll
                for (int g = 0; g < 4; ++g) {
                    int rv = (a[g] >= 0.f) ? 1 : 0;
                    rv += __shfl_xor(rv, 1);
                    rv += __shfl_xor(rv, 2);
                    rv += __shfl_xor(rv, 4);
                    rv += __shfl_xor(rv, 8);
                    if (nl == 0) atomicAdd(&rowc[wm * 64 + ti * 16 + rg * 4 + g], rv);
                }
            }
        }
    __syncthreads();
    if (tid < 128) {
        atomicAdd(&counts[j0 + tid], colc[tid]);
        if (bi != bj) atomicAdd(&counts[i0 + tid], rowc[tid]);
    }
}

// ---------------- kernel 3: argmin(counts) -> blended seed ----------------
__global__ void k_seed(const int* __restrict__ counts, const int* __restrict__ attn_seed,
                       int* __restrict__ seedp) {
    __shared__ int bestC[256];
    __shared__ int bestI[256];
    int tid = threadIdx.x;
    int bc = 0x7fffffff, bI = 0;
    for (int j = tid; j < NP; j += 256) {
        int c = counts[j];
        if (c < bc) { bc = c; bI = j; }
    }
    bestC[tid] = bc; bestI[tid] = bI;
    __syncthreads();
    for (int st = 128; st > 0; st >>= 1) {
        if (tid < st) {
            if (bestC[tid + st] < bestC[tid] ||
                (bestC[tid + st] == bestC[tid] && bestI[tid + st] < bestI[tid])) {
                bestC[tid] = bestC[tid + st];
                bestI[tid] = bestI[tid + st];
            }
        }
        __syncthreads();
    }
    if (tid == 0) {
        int flat = bestI[0];
        int sr = flat / WD, sc = flat % WD;
        int vr = sr + attn_seed[0];
        int vc = sc + attn_seed[1];
        int rr, rc;
        if ((vr & 1) == 0) rr = vr >> 1;
        else { int m = vr >> 1; rr = (m & 1) ? m + 1 : m; }   // round-half-to-even
        if ((vc & 1) == 0) rc = vc >> 1;
        else { int m = vc >> 1; rc = (m & 1) ? m + 1 : m; }
        seedp[0] = rr * WD + rc;
    }
}

// ---------------- kernel 4: sim[seed, :] row (fp32, exact) ----------------
__global__ __launch_bounds__(256) void k_simrow(const float* __restrict__ A,
                                                const int* __restrict__ seedp,
                                                float* __restrict__ simrow) {
    __shared__ float sv[DD];
    __shared__ float red[4];
    int seed = seedp[0];
    int tid = threadIdx.x;
    for (int k = tid; k < DD; k += 256) sv[k] = A[(size_t)seed * DD + k];
    __syncthreads();
    int jbase = blockIdx.x * 16;
    for (int jj = 0; jj < 16; jj++) {
        int j = jbase + jj;
        float p = 0.f;
        for (int k = tid; k < DD; k += 256) p += sv[k] * A[(size_t)j * DD + k];
        for (int o = 32; o > 0; o >>= 1) p += __shfl_down(p, o);
        if ((tid & 63) == 0) red[tid >> 6] = p;
        __syncthreads();
        if (tid == 0) simrow[j] = red[0] + red[1] + red[2] + red[3];
        __syncthreads();
    }
}

// ---------------- kernel 5: top-K selection + compact, parallel reductions ----------------
__device__ __forceinline__ int block_sum256(int v, int lane, int w, int* wred) {
#pragma unroll
    for (int o = 1; o < 64; o <<= 1) v += __shfl_xor(v, o);
    if (lane == 0) wred[w] = v;
    __syncthreads();
    int tt = wred[0] + wred[1] + wred[2] + wred[3];
    __syncthreads();
    return tt;
}
__device__ __forceinline__ int block_exscan256(int v, int lane, int w, int* wred,
                                               int* total) {
    int inc = v;
#pragma unroll
    for (int o = 1; o < 64; o <<= 1) { int u = __shfl_up(inc, o); if (lane >= o) inc += u; }
    if (lane == 63) wred[w] = inc;
    __syncthreads();
    int w0 = wred[0], w1 = wred[1], w2 = wred[2], w3 = wred[3];
    int wofs = (w > 0 ? w0 : 0) + (w > 1 ? w1 : 0) + (w > 2 ? w2 : 0);
    *total = w0 + w1 + w2 + w3;
    __syncthreads();
    return wofs + inc - v;   // exclusive
}

__global__ __launch_bounds__(256) void k_select(const float* __restrict__ simrow,
                                                const int* __restrict__ seedp,
                                                int* __restrict__ act, int* __restrict__ Mp) {
    __shared__ int wred[4];
    int tid = threadIdx.x, lane = tid & 63, w = tid >> 6;
    int base = tid * 16;
    unsigned key[16];
#pragma unroll
    for (int n = 0; n < 16; ++n) {
        unsigned b = __float_as_uint(simrow[base + n]);
        key[n] = (b & 0x80000000u) ? ~b : (b | 0x80000000u);   // monotone encode
    }
    unsigned prefix = 0;
    for (int bit = 31; bit >= 0; --bit) {
        unsigned cand = prefix | (1u << bit);
        int c = 0;
#pragma unroll
        for (int n = 0; n < 16; ++n) c += (key[n] >= cand) ? 1 : 0;
        int tot = block_sum256(c, lane, w, wred);
        if (tot >= KTOP) prefix = cand;
    }
    unsigned KT = prefix;   // Kth-largest key value
    int cgt = 0, ceq = 0;
#pragma unroll
    for (int n = 0; n < 16; ++n) {
        cgt += (key[n] > KT) ? 1 : 0;
        ceq += (key[n] == KT) ? 1 : 0;
    }
    int totgt = block_sum256(cgt, lane, w, wred);
    int slots = KTOP - totgt;   // #(==KT) elements (in index order) kept in top-K
    int dummy;
    int eqrun = block_exscan256(ceq, lane, w, wred, &dummy);
    int seed = seedp[0];
    int flag[16]; int cf = 0;
#pragma unroll
    for (int n = 0; n < 16; ++n) {
        int j = base + n;
        unsigned k = key[n];
        int topk = (k > KT) || (k == KT && eqrun < slots);
        if (k == KT) ++eqrun;
        int f = (topk && (k >= 0x80000000u || j == seed)) ? 1 : 0;   // sim>=0 or seed
        flag[n] = f; cf += f;
    }
    int M;
    int off = block_exscan256(cf, lane, w, wred, &M);
    if (tid == 0) Mp[0] = M;
#pragma unroll
    for (int n = 0; n < 16; ++n)
        if (flag[n]) act[off++] = base + n;
}

// ---------------- kernel 6: subsim rows, lane-parallel coalesced dots ----------------
__global__ __launch_bounds__(256) void k_subsim(const float* __restrict__ A,
                                                const int* __restrict__ act,
                                                const int* __restrict__ Mp,
                                                float* __restrict__ subsim) {
    __shared__ float av[DD];
    int M = Mp[0];
    int p = blockIdx.x;
    if (p >= M) return;
    int tid = threadIdx.x, lane = tid & 63, w = tid >> 6;
    int ip = act[p];
    for (int k = tid; k < DD; k += 256) av[k] = A[(size_t)ip * DD + k];
    __syncthreads();
    for (int q = w; q < M; q += 4) {
        int iq = act[q];
        float sum = 0.f;
        for (int k = lane; k < DD; k += 64) sum += av[k] * A[(size_t)iq * DD + k];
        for (int o = 32; o > 0; o >>= 1) sum += __shfl_down(sum, o);
        if (lane == 0) subsim[p * 128 + q] = sum;
    }
}

// ---------------- kernel 7: expansion scan (LDS) + CC on <=100 nodes ----------------
__global__ __launch_bounds__(256) void k_finish(const float* __restrict__ subsim,
                                                const int* __restrict__ act,
                                                const int* __restrict__ Mp,
                                                int* __restrict__ outp) {
    __shared__ float ss[128 * 128];   // 64 KB
    __shared__ int alive[128];
    __shared__ int lab[128];
    __shared__ int yy[128], xx[128];
    __shared__ int chg;
    int M = Mp[0];
    int tid = threadIdx.x;

    for (int idx = tid; idx < M * 128; idx += 256) ss[idx] = subsim[idx];
    if (tid < 128) alive[tid] = 0;
    __syncthreads();

    // sequential expansion scan, wave 0 only (LDS-resident)
    if (tid < 64) {
        int lane = tid;
        float al = (lane < M) ? 1.f : 0.f;
        float ah = (lane + 64 < M) ? 1.f : 0.f;
        for (int p = 0; p < M; p++) {
            float part = 0.f;
            if (lane < M)      part += ss[p * 128 + lane] * al;
            if (lane + 64 < M) part += ss[p * 128 + lane + 64] * ah;
#pragma unroll
            for (int o = 1; o < 64; o <<= 1) part += __shfl_xor(part, o);
            if (!(part > 0.f)) {
                if (lane == p)      al = 0.f;
                if (lane + 64 == p) ah = 0.f;
            }
        }
        alive[lane] = (lane < M && al != 0.f) ? 1 : 0;
        alive[lane + 64] = (lane + 64 < M && ah != 0.f) ? 1 : 0;
    }
    __syncthreads();

    // connected components over alive nodes (8-connectivity, min-label)
    if (tid < 128) {
        int a = (tid < M) ? alive[tid] : 0;
        int id = a ? act[tid] : 0;
        yy[tid] = a ? (id >> 6) : -1000;
        xx[tid] = a ? (id & 63) : -1000;
        lab[tid] = a ? (id + 1) : BIGL;
    }
    __syncthreads();
    while (true) {
        if (tid == 0) chg = 0;
        __syncthreads();
        int local = 0;
        if (tid < M && alive[tid]) {
            int m = lab[tid];
            int y = yy[tid], x = xx[tid];
            for (int q = 0; q < M; q++) {
                int dy = yy[q] - y;
                if (dy < -1 || dy > 1) continue;
                int dx = xx[q] - x;
                if (dx < -1 || dx > 1) continue;
                int u = lab[q];
                if (u < m) m = u;
            }
            if (m < lab[tid]) { lab[tid] = m; local = 1; }
        }
        if (local) chg = 1;
        __syncthreads();
        if (chg == 0) break;
        __syncthreads();
    }

    for (int n = tid; n < NP; n += 256) outp[n] = 0;
    __syncthreads();
    if (tid < M && alive[tid]) outp[act[tid]] = lab[tid];
}

extern "C" void kernel_launch(void* const* d_in, const int* in_sizes, int n_in,
                              void* d_out, int out_size, void* d_ws, size_t ws_size,
                              hipStream_t stream) {
    const float* A = (const float*)d_in[0];       // out: (4096, 768) fp32
    const int* attn = (const int*)d_in[1];        // attn_seed: (2,) int32
    int* outp = (int*)d_out;                      // labels: (64,64) int32

    char* ws = (char*)d_ws;
    int*            counts = (int*)(ws);                    // 16 KB
    float*          simrow = (float*)(ws + 16384);          // 16 KB
    int*            act    = (int*)(ws + 32768);            // 512 B
    int*            Mp     = (int*)(ws + 33280);
    int*            seedp  = (int*)(ws + 33284);
    float*          subsim = (float*)(ws + 33792);          // 64 KB
    unsigned short* hi     = (unsigned short*)(ws + 1048576);           // 6.29 MB
    unsigned short* lo     = (unsigned short*)(ws + 1048576 + 6291456); // 6.29 MB

    k_split  <<<3072, 256, 0, stream>>>(A, hi, lo, counts);
    k_gemm   <<<528,  256, 0, stream>>>(hi, lo, counts);
    k_seed   <<<1,    256, 0, stream>>>(counts, attn, seedp);
    k_simrow <<<256,  256, 0, stream>>>(A, seedp, simrow);
    k_select <<<1,    256, 0, stream>>>(simrow, seedp, act, Mp);
    k_subsim <<<128,  256, 0, stream>>>(A, act, Mp, subsim);
    k_finish <<<1,    256, 0, stream>>>(subsim, act, Mp, outp);
}

// Round 5
// 291.377 us; speedup vs baseline: 1.8180x; 1.1434x over previous
//
#include <hip/hip_runtime.h>
#include <cstdint>

#define NP   4096      // patches
#define DD   768       // embed dim
#define HD   64
#define WD   64
#define KTOP 100
#define BIGL 4097      // N+1
#define NBLK 256       // k_tail grid

typedef short bf16x8 __attribute__((ext_vector_type(8)));
typedef float f32x4  __attribute__((ext_vector_type(4)));

__device__ __forceinline__ void gload_lds16(const void* g, void* l) {
    __builtin_amdgcn_global_load_lds(
        (const __attribute__((address_space(1))) unsigned int*)(uintptr_t)g,
        (__attribute__((address_space(3))) unsigned int*)(unsigned int)(uintptr_t)l,
        16, 0, 0);
}

__device__ __forceinline__ unsigned short f2bf_rne(float x) {
    unsigned b = __float_as_uint(x);
    unsigned r = b + 0x7FFFu + ((b >> 16) & 1u);
    return (unsigned short)(r >> 16);
}
__device__ __forceinline__ float bf2f(unsigned short h) {
    return __uint_as_float(((unsigned)h) << 16);
}

// ---------------- kernel 1: split A into bf16 hi+lo; zero counts & barriers ----------------
__global__ __launch_bounds__(256) void k_split(const float* __restrict__ A,
                                               unsigned short* __restrict__ hi,
                                               unsigned short* __restrict__ lo,
                                               int* __restrict__ counts,
                                               int* __restrict__ bar) {
    if (blockIdx.x < 16) counts[blockIdx.x * 256 + threadIdx.x] = 0;
    if (blockIdx.x == 16 && threadIdx.x < 16) bar[threadIdx.x] = 0;
    int idx = blockIdx.x * 256 + threadIdx.x;       // float4 index
    float4 v = ((const float4*)A)[idx];
    unsigned short h0 = f2bf_rne(v.x), h1 = f2bf_rne(v.y),
                   h2 = f2bf_rne(v.z), h3 = f2bf_rne(v.w);
    unsigned short l0 = f2bf_rne(v.x - bf2f(h0)), l1 = f2bf_rne(v.y - bf2f(h1)),
                   l2 = f2bf_rne(v.z - bf2f(h2)), l3 = f2bf_rne(v.w - bf2f(h3));
    ((ushort4*)hi)[idx] = make_ushort4(h0, h1, h2, h3);
    ((ushort4*)lo)[idx] = make_ushort4(l0, l1, l2, l3);
}

// ---------------- kernel 2: split-bf16 MFMA GEMM, double-buffered BK=64 ----------------
// LDS rows: 64 bf16 = 128B = 8 chunks of 16B; XOR swizzle kc^(row&7) -> conflict-free.
__device__ __forceinline__ void stage_tile(const unsigned short* __restrict__ aS,
                                           const unsigned short* __restrict__ bS,
                                           int i0, int j0, int kbase, int tid,
                                           unsigned short* As, unsigned short* Bs) {
#pragma unroll
    for (int q = 0; q < 4; ++q) {
        int p = q * 256 + tid;               // 16B chunk id, 1024 per tile
        int row = p >> 3, kcp = p & 7;
        int kclog = kcp ^ (row & 7);
        gload_lds16(aS + (size_t)(i0 + row) * DD + kbase + kclog * 8, As + p * 8);
        gload_lds16(bS + (size_t)(j0 + row) * DD + kbase + kclog * 8, Bs + p * 8);
    }
}

__global__ __launch_bounds__(256) void k_gemm(const unsigned short* __restrict__ hi,
                                              const unsigned short* __restrict__ lo,
                                              int* __restrict__ counts) {
    __shared__ __align__(16) unsigned short As[2][128 * 64];   // 2 x 16 KB
    __shared__ __align__(16) unsigned short Bs[2][128 * 64];   // 2 x 16 KB
    __shared__ int colc[128];
    __shared__ int rowc[128];

    // XCD-locality supertile remap (XCD = blockIdx%8 round-robin):
    int t = ((blockIdx.x & 7) * 66) + (blockIdx.x >> 3);
    int SI = 0, SJ = 0, rem = t;
    for (;;) {
        int sz = (SI == SJ) ? 36 : 64;
        if (rem < sz) break;
        rem -= sz;
        if (++SJ == 4) { ++SI; SJ = SI; }
    }
    int li, lj;
    if (SI == SJ) {
        int r = 0;
        while (rem >= (8 - r)) { rem -= (8 - r); ++r; }
        li = r; lj = r + rem;
    } else { li = rem >> 3; lj = rem & 7; }
    int bi = SI * 8 + li, bj = SJ * 8 + lj;
    int i0 = bi * 128, j0 = bj * 128;

    int tid = threadIdx.x;
    int lane = tid & 63, w = tid >> 6;
    int wm = w & 1, wn = w >> 1;      // wave quadrant: rows wm*64, cols wn*64

    f32x4 acc[4][4];
#pragma unroll
    for (int ti = 0; ti < 4; ++ti)
#pragma unroll
        for (int tj = 0; tj < 4; ++tj) { acc[ti][tj][0] = 0.f; acc[ti][tj][1] = 0.f;
                                         acc[ti][tj][2] = 0.f; acc[ti][tj][3] = 0.f; }

    stage_tile(hi, hi, i0, j0, 0, tid, As[0], Bs[0]);   // prologue: it=0 -> buf0
    for (int it = 0; it < 36; ++it) {
        int cur = it & 1;
        __syncthreads();   // drains vmcnt: buf[cur] loads done; prev compute on buf[cur^1] done
        if (it + 1 < 36) {
            int seg = (it + 1) / 12;           // 0: hi.hi  1: lo.hi  2: hi.lo
            int kb = ((it + 1) % 12) * 64;
            const unsigned short* aS = (seg == 1) ? lo : hi;
            const unsigned short* bS = (seg == 2) ? lo : hi;
            stage_tile(aS, bS, i0, j0, kb, tid, As[cur ^ 1], Bs[cur ^ 1]);
        }
#pragma unroll
        for (int s = 0; s < 2; ++s) {
            bf16x8 af[4], bfr[4];
#pragma unroll
            for (int tt = 0; tt < 4; ++tt) {
                int arow = wm * 64 + tt * 16 + (lane & 15);
                int kc = s * 4 + (lane >> 4);
                int pa = arow * 8 + (kc ^ (arow & 7));
                af[tt] = *(const bf16x8*)&As[cur][pa * 8];
                int brow = wn * 64 + tt * 16 + (lane & 15);
                int pb = brow * 8 + (kc ^ (brow & 7));
                bfr[tt] = *(const bf16x8*)&Bs[cur][pb * 8];
            }
#pragma unroll
            for (int ti = 0; ti < 4; ++ti)
#pragma unroll
                for (int tj = 0; tj < 4; ++tj)
                    acc[ti][tj] = __builtin_amdgcn_mfma_f32_16x16x32_bf16(
                        af[ti], bfr[tj], acc[ti][tj], 0, 0, 0);
        }
    }

    if (tid < 128) { colc[tid] = 0; rowc[tid] = 0; }
    __syncthreads();

    int nl = lane & 15;     // col within 16x16 tile
    int rg = lane >> 4;     // row group (rows rg*4 + reg)
#pragma unroll
    for (int ti = 0; ti < 4; ++ti)
#pragma unroll
        for (int tj = 0; tj < 4; ++tj) {
            f32x4 a = acc[ti][tj];
            int ct = ((a[0] >= 0.f) ? 1 : 0) + ((a[1] >= 0.f) ? 1 : 0) +
                     ((a[2] >= 0.f) ? 1 : 0) + ((a[3] >= 0.f) ? 1 : 0);
            ct += __shfl_xor(ct, 16);
            ct += __shfl_xor(ct, 32);
            if (rg == 0) atomicAdd(&colc[wn * 64 + tj * 16 + nl], ct);
            if (bi != bj) {
#pragma unroll
                for (int g = 0; g < 4; ++g) {
                    int rv = (a[g] >= 0.f) ? 1 : 0;
                    rv += __shfl_xor(rv, 1);
                    rv += __shfl_xor(rv, 2);
                    rv += __shfl_xor(rv, 4);
                    rv += __shfl_xor(rv, 8);
                    if (nl == 0) atomicAdd(&rowc[wm * 64 + ti * 16 + rg * 4 + g], rv);
                }
            }
        }
    __syncthreads();
    if (tid < 128) {
        atomicAdd(&counts[j0 + tid], colc[tid]);
        if (bi != bj) atomicAdd(&counts[i0 + tid], rowc[tid]);
    }
}

// ---------------- fused tail: seed -> simrow -> select -> subsim -> expand+CC ----------------
__device__ __forceinline__ void grid_barrier(int* bar, int idx) {
    __syncthreads();
    if (threadIdx.x == 0) {
        __threadfence();                       // release
        atomicAdd(&bar[idx], 1);
        while (atomicAdd(&bar[idx], 0) < NBLK) __builtin_amdgcn_s_sleep(8);
        __threadfence();                       // acquire
    }
    __syncthreads();
}

__device__ __forceinline__ int block_sum256(int v, int lane, int w, int* wred) {
#pragma unroll
    for (int o = 1; o < 64; o <<= 1) v += __shfl_xor(v, o);
    if (lane == 0) wred[w] = v;
    __syncthreads();
    int tt = wred[0] + wred[1] + wred[2] + wred[3];
    __syncthreads();
    return tt;
}
__device__ __forceinline__ int block_exscan256(int v, int lane, int w, int* wred,
                                               int* total) {
    int inc = v;
#pragma unroll
    for (int o = 1; o < 64; o <<= 1) { int u = __shfl_up(inc, o); if (lane >= o) inc += u; }
    if (lane == 63) wred[w] = inc;
    __syncthreads();
    int w0 = wred[0], w1 = wred[1], w2 = wred[2], w3 = wred[3];
    int wofs = (w > 0 ? w0 : 0) + (w > 1 ? w1 : 0) + (w > 2 ? w2 : 0);
    *total = w0 + w1 + w2 + w3;
    __syncthreads();
    return wofs + inc - v;   // exclusive
}

__global__ __launch_bounds__(256) void k_tail(const float* __restrict__ A,
                                              const int* __restrict__ counts,
                                              const int* __restrict__ attn_seed,
                                              float* __restrict__ simrow,
                                              int* __restrict__ act, int* __restrict__ Mp,
                                              int* __restrict__ seedp,
                                              float* __restrict__ subsim,
                                              int* __restrict__ bar,
                                              int* __restrict__ outp) {
    __shared__ float ss[128 * 128];   // 64 KB: av (stage D) / subsim (stage E)
    __shared__ int ired[256];
    __shared__ int wred[4];
    __shared__ int alive[128];
    __shared__ int lab[128];
    __shared__ int yyv[128], xxv[128];
    __shared__ int chg;
    int tid = threadIdx.x, lane = tid & 63, w = tid >> 6;
    int blk = blockIdx.x;

    // ---- stage A: block 0: argmin(counts) -> blended seed ----
    if (blk == 0) {
        int bc = 0x7fffffff, bI = 0;
        for (int j = tid; j < NP; j += 256) {
            int c = counts[j];
            if (c < bc) { bc = c; bI = j; }
        }
        ired[tid] = bc; ired[tid] = bc;
        __shared__ int bestC[256]; __shared__ int bestI[256];
        bestC[tid] = bc; bestI[tid] = bI;
        __syncthreads();
        for (int st = 128; st > 0; st >>= 1) {
            if (tid < st) {
                if (bestC[tid + st] < bestC[tid] ||
                    (bestC[tid + st] == bestC[tid] && bestI[tid + st] < bestI[tid])) {
                    bestC[tid] = bestC[tid + st];
                    bestI[tid] = bestI[tid + st];
                }
            }
            __syncthreads();
        }
        if (tid == 0) {
            int flat = bestI[0];
            int sr = flat / WD, sc = flat % WD;
            int vr = sr + attn_seed[0];
            int vc = sc + attn_seed[1];
            int rr, rc;
            if ((vr & 1) == 0) rr = vr >> 1;
            else { int m = vr >> 1; rr = (m & 1) ? m + 1 : m; }   // round-half-to-even
            if ((vc & 1) == 0) rc = vc >> 1;
            else { int m = vc >> 1; rc = (m & 1) ? m + 1 : m; }
            atomicExch(seedp, rr * WD + rc);
        }
    }
    grid_barrier(bar, 0);
    int seed = atomicAdd(seedp, 0);

    // ---- stage B: all blocks: simrow, 16 entries per block (4 per wave) ----
    {
        int jbase = blk * 16 + w * 4;
        for (int jj = 0; jj < 4; ++jj) {
            int j = jbase + jj;
            float sum = 0.f;
#pragma unroll
            for (int kk = 0; kk < 12; ++kk) {
                int k = lane + kk * 64;
                sum += A[(size_t)seed * DD + k] * A[(size_t)j * DD + k];
            }
#pragma unroll
            for (int o = 32; o > 0; o >>= 1) sum += __shfl_down(sum, o);
            if (lane == 0) simrow[j] = sum;
        }
    }
    grid_barrier(bar, 1);

    // ---- stage C: block 0: top-K select + compact; blocks >=128: zero outp ----
    if (blk == 0) {
        int base = tid * 16;
        unsigned key[16];
#pragma unroll
        for (int n = 0; n < 16; ++n) {
            unsigned b = __float_as_uint(simrow[base + n]);
            key[n] = (b & 0x80000000u) ? ~b : (b | 0x80000000u);   // monotone encode
        }
        unsigned prefix = 0;
        for (int bit = 31; bit >= 0; --bit) {
            unsigned cand = prefix | (1u << bit);
            int c = 0;
#pragma unroll
            for (int n = 0; n < 16; ++n) c += (key[n] >= cand) ? 1 : 0;
            int tot = block_sum256(c, lane, w, wred);
            if (tot >= KTOP) prefix = cand;
        }
        unsigned KT = prefix;   // Kth-largest key
        int cgt = 0, ceq = 0;
#pragma unroll
        for (int n = 0; n < 16; ++n) {
            cgt += (key[n] > KT) ? 1 : 0;
            ceq += (key[n] == KT) ? 1 : 0;
        }
        int totgt = block_sum256(cgt, lane, w, wred);
        int slots = KTOP - totgt;   // #(==KT) kept, in index order
        int dummy;
        int eqrun = block_exscan256(ceq, lane, w, wred, &dummy);
        int flag[16]; int cf = 0;
#pragma unroll
        for (int n = 0; n < 16; ++n) {
            int j = base + n;
            unsigned k = key[n];
            int topk = (k > KT) || (k == KT && eqrun < slots);
            if (k == KT) ++eqrun;
            int f = (topk && (k >= 0x80000000u || j == seed)) ? 1 : 0;   // sim>=0 or seed
            flag[n] = f; cf += f;
        }
        int M;
        int off = block_exscan256(cf, lane, w, wred, &M);
        if (tid == 0) atomicExch(Mp, M);
#pragma unroll
        for (int n = 0; n < 16; ++n)
            if (flag[n]) act[off++] = base + n;
    } else if (blk >= 128) {
        int n = (blk - 128) * 32 + (tid & 31);
        outp[n * 1] = 0;
        // each of 128 blocks zeros 32 ints x ... need full 4096: 128 blocks x 32 = 4096
    }
    grid_barrier(bar, 2);
    int M = atomicAdd(Mp, 0);

    // ---- stage D: blocks 0..127: subsim row p ----
    if (blk < 128 && blk < M) {
        int p = blk;
        int ip = act[p];
        for (int k = tid; k < DD; k += 256) ss[k] = A[(size_t)ip * DD + k];
        __syncthreads();
        for (int q = w; q < M; q += 4) {
            int iq = act[q];
            float sum = 0.f;
#pragma unroll
            for (int kk = 0; kk < 12; ++kk) {
                int k = lane + kk * 64;
                sum += ss[k] * A[(size_t)iq * DD + k];
            }
#pragma unroll
            for (int o = 32; o > 0; o >>= 1) sum += __shfl_down(sum, o);
            if (lane == 0) subsim[p * 128 + q] = sum;
        }
    }
    grid_barrier(bar, 3);

    // ---- stage E: block 0: expansion scan + CC over alive nodes ----
    if (blk != 0) return;
    for (int idx = tid; idx < M * 128; idx += 256) ss[idx] = subsim[idx];
    if (tid < 128) alive[tid] = 0;
    __syncthreads();

    if (tid < 64) {
        float al = (lane < M) ? 1.f : 0.f;
        float ah = (lane + 64 < M) ? 1.f : 0.f;
        for (int p = 0; p < M; p++) {
            float part = 0.f;
            if (lane < M)      part += ss[p * 128 + lane] * al;
            if (lane + 64 < M) part += ss[p * 128 + lane + 64] * ah;
#pragma unroll
            for (int o = 1; o < 64; o <<= 1) part += __shfl_xor(part, o);
            if (!(part > 0.f)) {
                if (lane == p)      al = 0.f;
                if (lane + 64 == p) ah = 0.f;
            }
        }
        alive[lane] = (lane < M && al != 0.f) ? 1 : 0;
        alive[lane + 64] = (lane + 64 < M && ah != 0.f) ? 1 : 0;
    }
    __syncthreads();

    if (tid < 128) {
        int a = (tid < M) ? alive[tid] : 0;
        int id = a ? act[tid] : 0;
        yyv[tid] = a ? (id >> 6) : -1000;
        xxv[tid] = a ? (id & 63) : -1000;
        lab[tid] = a ? (id + 1) : BIGL;
    }
    __syncthreads();
    while (true) {
        if (tid == 0) chg = 0;
        __syncthreads();
        int local = 0;
        if (tid < M && alive[tid]) {
            int m = lab[tid];
            int y = yyv[tid], x = xxv[tid];
            for (int q = 0; q < M; q++) {
                int dy = yyv[q] - y;
                if (dy < -1 || dy > 1) continue;
                int dx = xxv[q] - x;
                if (dx < -1 || dx > 1) continue;
                int u = lab[q];
                if (u < m) m = u;
            }
            if (m < lab[tid]) { lab[tid] = m; local = 1; }
        }
        if (local) chg = 1;
        __syncthreads();
        if (chg == 0) break;
        __syncthreads();
    }
    if (tid < M && alive[tid]) outp[act[tid]] = lab[tid];
}

extern "C" void kernel_launch(void* const* d_in, const int* in_sizes, int n_in,
                              void* d_out, int out_size, void* d_ws, size_t ws_size,
                              hipStream_t stream) {
    const float* A = (const float*)d_in[0];       // out: (4096, 768) fp32
    const int* attn = (const int*)d_in[1];        // attn_seed: (2,) int32
    int* outp = (int*)d_out;                      // labels: (64,64) int32

    char* ws = (char*)d_ws;
    int*            counts = (int*)(ws);                    // 16 KB
    float*          simrow = (float*)(ws + 16384);          // 16 KB
    int*            act    = (int*)(ws + 32768);            // 512 B
    int*            Mp     = (int*)(ws + 33280);
    int*            seedp  = (int*)(ws + 33284);
    int*            bar    = (int*)(ws + 33344);            // 16 ints (64B-aligned)
    float*          subsim = (float*)(ws + 33792);          // 64 KB
    unsigned short* hi     = (unsigned short*)(ws + 1048576);           // 6.29 MB
    unsigned short* lo     = (unsigned short*)(ws + 1048576 + 6291456); // 6.29 MB

    k_split <<<3072, 256, 0, stream>>>(A, hi, lo, counts, bar);
    k_gemm  <<<528,  256, 0, stream>>>(hi, lo, counts);
    k_tail  <<<NBLK, 256, 0, stream>>>(A, counts, attn, simrow, act, Mp, seedp,
                                       subsim, bar, outp);
}